// Round 7
// baseline (967.128 us; speedup 1.0000x reference)
//
#include <hip/hip_runtime.h>
#include <math.h>

#define TSTEPS 288
#define NTHREADS 1024

typedef float f32x2 __attribute__((ext_vector_type(2)));

__device__ __forceinline__ float sigmoidf_(float x) {
    return 1.0f / (1.0f + __expf(-x));
}

// Packed 2xf32 FMA: one VALU issue slot for two MACs.
__device__ __forceinline__ void pkfma(f32x2& acc, f32x2 w, f32x2 x) {
    asm("v_pk_fma_f32 %0, %1, %2, %0" : "+v"(acc) : "v"(w), "v"(x));
}

// Butterfly all-reduce over the low log2(NS) lane bits (seg bits).
template<int NS>
__device__ __forceinline__ float allreduce_seg(float v) {
    if constexpr (NS > 1)
        v += __int_as_float(__builtin_amdgcn_update_dpp(
                0, __float_as_int(v), 0xB1, 0xF, 0xF, true));   // quad_perm xor 1
    if constexpr (NS > 2)
        v += __int_as_float(__builtin_amdgcn_update_dpp(
                0, __float_as_int(v), 0x4E, 0xF, 0xF, true));   // quad_perm xor 2
    if constexpr (NS > 4)
        v += __int_as_float(__builtin_amdgcn_ds_swizzle(
                __float_as_int(v), 0x101F));                    // xor 4
    return v;
}

// Exchange with the gate-pair partner thread at lane distance NS (xor-NS).
template<int NS>
__device__ __forceinline__ float swz_pair(float v) {
    return __int_as_float(__builtin_amdgcn_ds_swizzle(
        __float_as_int(v), (NS << 10) | 0x1F));                 // xor NS
}

// Conflict-free LDS layout: float4 #k4 of segment seg lives at float offset
// (k4*NS+seg)*4. perm_idx maps logical element j -> stored float offset.
template<int NS, int KSEG>
__device__ __forceinline__ int perm_idx(int j) {
    return (((j % KSEG) >> 2) * NS + (j / KSEG)) * 4 + (j & 3);
}

// One block = one sample. tid = u*(2NS) + p*NS + seg.
//   u: unit, p: gate-pair (p=0 -> cols {u, U+u} = (i,f); p=1 -> {2U+u, 3U+u}
//   = (g,o)), seg: k-split segment over KIN input + KH hidden rows.
// Cross-seg reduce: in-wave butterfly. Gate-pair z exchange: one xor-NS
// swizzle. Gates computed redundantly on all 2NS lanes of a unit (bitwise
// identical; c replicated). One barrier per timestep; xh ping-pong.
template<int DIN, int U, int NS, int ACTIVE, int SEQNS, int SEQK,
         bool FIRST, bool WRITE_NOW, bool WRITE_DELAY>
__device__ void run_layer(const float* __restrict__ Wk,
                          const float* __restrict__ Wr,
                          const float* __restrict__ bias,
                          const float* __restrict__ xg,   // x + b*T*64 (FIRST only)
                          float* __restrict__ seq,
                          float* __restrict__ xh,         // 2 x 128 ping-pong
                          float* __restrict__ xring,      // 2 x 64 input ring
                          int tid)
{
    constexpr int KIN  = DIN / NS;
    constexpr int KH   = U / NS;
    constexpr int COLS = 4 * U;
    constexpr int LOG  = (NS == 4) ? 2 : 3;
    constexpr int NPI  = KIN / 2;
    constexpr int NPH  = KH / 2;
    constexpr int NP   = NPI + NPH;
    static_assert(ACTIVE == 2 * U * NS, "thread mapping");
    static_assert(KIN % 4 == 0 && KH % 4 == 0, "float4 alignment");
    static_assert(NS == 4 || NS == 8, "butterfly width");

    const int seg = tid & (NS - 1);
    const int p   = (tid >> LOG) & 1;
    const int u   = tid >> (LOG + 1);
    const bool act = tid < ACTIVE;

    f32x2 w[2][NP];
    float bz[2] = {0.f, 0.f};
    float cst = 0.0f, hprev = 0.0f;

    if (act) {
        const int colA = (2 * p) * U + u;        // i (p=0) / g (p=1)
        const int colB = (2 * p + 1) * U + u;    // f (p=0) / o (p=1)
#pragma unroll
        for (int q = 0; q < NPI; ++q) {
            const int k0 = seg * KIN + 2 * q;
            w[0][q] = f32x2{Wk[(size_t)k0 * COLS + colA],
                            Wk[(size_t)(k0 + 1) * COLS + colA]};
            w[1][q] = f32x2{Wk[(size_t)k0 * COLS + colB],
                            Wk[(size_t)(k0 + 1) * COLS + colB]};
        }
#pragma unroll
        for (int q = 0; q < NPH; ++q) {
            const int k0 = seg * KH + 2 * q;
            w[0][NPI + q] = f32x2{Wr[(size_t)k0 * COLS + colA],
                                  Wr[(size_t)(k0 + 1) * COLS + colA]};
            w[1][NPI + q] = f32x2{Wr[(size_t)k0 * COLS + colB],
                                  Wr[(size_t)(k0 + 1) * COLS + colB]};
        }
        bz[0] = bias[colA];
        bz[1] = bias[colB];
        // Pin weight pairs in registers (defeats remat/sinking).
#pragma unroll
        for (int g = 0; g < 2; ++g)
#pragma unroll
            for (int q = 0; q < NP; ++q)
                asm volatile("" : "+v"(w[g][q]));
    }
    if (tid < 128) xh[tid] = 0.0f;                 // zero t=0 read buffer
    if (FIRST && tid < 64)                         // stage x row 0 (permuted)
        xring[perm_idx<4, 16>(tid)] = xg[tid];
    __syncthreads();

    for (int t = 0; t < TSTEPS; ++t) {
        if (act) {
            const float* __restrict__ xr = xh + (t & 1) * 128;
            float* __restrict__ xw       = xh + ((t + 1) & 1) * 128;

            // L1 input staging: 64 threads fetch row t+1 (coalesced 256B).
            float xstage = 0.0f;
            if (FIRST && tid < 64 && (t + 1) < TSTEPS)
                xstage = xg[(t + 1) * 64 + tid];

            f32x2 ac0 = {0.f, 0.f}, ac1 = {0.f, 0.f};

            // ---- input-projection part (conflict-free strided float4) ----
            {
                const float4* in4 = reinterpret_cast<const float4*>(
                    FIRST ? (xring + (t & 1) * 64) : (seq + t * 128)) + seg;
#pragma unroll
                for (int k4 = 0; k4 < KIN / 4; ++k4) {
                    const float4 v = in4[k4 * NS];
                    const f32x2 lo = {v.x, v.y}, hi = {v.z, v.w};
                    pkfma(ac0, w[0][2*k4+0], lo); pkfma(ac0, w[0][2*k4+1], hi);
                    pkfma(ac1, w[1][2*k4+0], lo); pkfma(ac1, w[1][2*k4+1], hi);
                }
            }
            // ---- recurrent part ----
            {
                const float4* h4 = reinterpret_cast<const float4*>(xr) + seg;
#pragma unroll
                for (int k4 = 0; k4 < KH / 4; ++k4) {
                    const float4 v = h4[k4 * NS];
                    const f32x2 lo = {v.x, v.y}, hi = {v.z, v.w};
                    const int pb = NPI + 2 * k4;
                    pkfma(ac0, w[0][pb], lo); pkfma(ac0, w[0][pb+1], hi);
                    pkfma(ac1, w[1][pb], lo); pkfma(ac1, w[1][pb+1], hi);
                }
            }

            // ---- horizontal, butterfly over segs, bias ----
            float a0 = (ac0[0] + ac0[1]);
            float a1 = (ac1[0] + ac1[1]);
            a0 = allreduce_seg<NS>(a0) + bz[0];
            a1 = allreduce_seg<NS>(a1) + bz[1];

            // ---- gate-pair exchange: partner thread has the other 2 z's ----
            const float r0 = swz_pair<NS>(a0);
            const float r1 = swz_pair<NS>(a1);
            const float zi = p ? r0 : a0;
            const float zf = p ? r1 : a1;
            const float zg = p ? a0 : r0;
            const float zo = p ? a1 : r1;

            if constexpr (WRITE_DELAY) {
                if (seg == 0 && p == 0 && t > 0)
                    seq[(t - 1) * 128 + perm_idx<SEQNS, SEQK>(u)] = hprev;
            }

            // ---- gate update (redundant across the unit's 2NS lanes) ----
            const float gi = sigmoidf_(zi);
            const float gf = sigmoidf_(zf);
            const float gg = fmaxf(zg, 0.0f);          // cell activation = relu
            const float go = sigmoidf_(zo);
            cst = fmaf(gf, cst, gi * gg);
            const float h = go * fmaxf(cst, 0.0f);     // output activation = relu

            if (seg == 0 && p == 0) {
                xw[perm_idx<NS, KH>(u)] = h;
                if constexpr (WRITE_NOW)
                    seq[t * 128 + perm_idx<SEQNS, SEQK>(u)] = h;
            }
            hprev = h;

            if (FIRST && tid < 64 && (t + 1) < TSTEPS)
                xring[((t + 1) & 1) * 64 + perm_idx<4, 16>(tid)] = xstage;
        }
        __syncthreads();
    }

    if constexpr (WRITE_DELAY) {
        if (act && seg == 0 && p == 0)
            seq[(TSTEPS - 1) * 128 + perm_idx<SEQNS, SEQK>(u)] = hprev;
    }
}

extern "C" __global__ void __launch_bounds__(NTHREADS, 4)
lstm_stack_kernel(const float* __restrict__ x,
                  const float* __restrict__ W1, const float* __restrict__ U1, const float* __restrict__ b1,
                  const float* __restrict__ W2, const float* __restrict__ U2, const float* __restrict__ b2,
                  const float* __restrict__ W3, const float* __restrict__ U3, const float* __restrict__ b3,
                  const float* __restrict__ W4, const float* __restrict__ U4, const float* __restrict__ b4,
                  const float* __restrict__ Wf, const float* __restrict__ bf,
                  const float* __restrict__ Wo, const float* __restrict__ bo,
                  float* __restrict__ out)
{
    __shared__ __align__(16) float seq[TSTEPS * 128];   // 147456 B
    __shared__ __align__(16) float xh[256 + 16];        // ping-pong h + head tmp
    __shared__ __align__(16) float xring[2 * 64];       // L1 input ring

    const int tid = threadIdx.x;
    const float* xg = x + (size_t)blockIdx.x * TSTEPS * 64;

    //            DIN    U NS ACTIVE SEQNS SEQK  FIRST  NOW    DELAY
    run_layer< 64, 128, 4, 1024, 8, 16, true , true , false>(W1, U1, b1, xg, seq, xh, xring, tid);
    __syncthreads();
    run_layer<128,  64, 8, 1024, 8,  8, false, false, true >(W2, U2, b2, xg, seq, xh, xring, tid);
    __syncthreads();
    run_layer< 64,  64, 8, 1024, 8,  8, false, false, true >(W3, U3, b3, xg, seq, xh, xring, tid);
    __syncthreads();
    run_layer< 64,  32, 8,  512, 8,  8, false, false, false>(W4, U4, b4, xg, seq, xh, xring, tid);
    __syncthreads();

    // ---- FC head: h4 final in xh[0..32) (L4's perm<8,4> is identity; T even) ----
    if (tid < 16) {
        float acc = bf[tid];
#pragma unroll
        for (int k = 0; k < 32; ++k) acc = fmaf(xh[k], Wf[k * 16 + tid], acc);
        xh[256 + tid] = fmaxf(acc, 0.0f);
    }
    __syncthreads();
    if (tid == 0) {
        float acc = bo[0];
#pragma unroll
        for (int k = 0; k < 16; ++k) acc = fmaf(xh[256 + k], Wo[k], acc);
        out[blockIdx.x] = acc;
    }
}

extern "C" void kernel_launch(void* const* d_in, const int* in_sizes, int n_in,
                              void* d_out, int out_size, void* d_ws, size_t ws_size,
                              hipStream_t stream) {
    const float* x  = (const float*)d_in[0];
    const float* W1 = (const float*)d_in[1];
    const float* U1 = (const float*)d_in[2];
    const float* b1 = (const float*)d_in[3];
    const float* W2 = (const float*)d_in[4];
    const float* U2 = (const float*)d_in[5];
    const float* b2 = (const float*)d_in[6];
    const float* W3 = (const float*)d_in[7];
    const float* U3 = (const float*)d_in[8];
    const float* b3 = (const float*)d_in[9];
    const float* W4 = (const float*)d_in[10];
    const float* U4 = (const float*)d_in[11];
    const float* b4 = (const float*)d_in[12];
    const float* Wf = (const float*)d_in[13];
    const float* bf = (const float*)d_in[14];
    const float* Wo = (const float*)d_in[15];
    const float* bo = (const float*)d_in[16];
    float* out = (float*)d_out;

    lstm_stack_kernel<<<dim3(256), dim3(NTHREADS), 0, stream>>>(
        x, W1, U1, b1, W2, U2, b2, W3, U3, b3, W4, U4, b4, Wf, bf, Wo, bo, out);
}

// Round 8
// 576.170 us; speedup vs baseline: 1.6785x; 1.6785x over previous
//
#include <hip/hip_runtime.h>
#include <math.h>

#define TSTEPS 288
#define NTHREADS 512

typedef float f32x2 __attribute__((ext_vector_type(2)));

__device__ __forceinline__ float sigmoidf_(float x) {
    return 1.0f / (1.0f + __expf(-x));
}

// Packed 2xf32 FMA: one VALU issue slot for two MACs.
__device__ __forceinline__ void pkfma(f32x2& acc, f32x2 w, f32x2 x) {
    asm("v_pk_fma_f32 %0, %1, %2, %0" : "+v"(acc) : "v"(w), "v"(x));
}

// Butterfly all-reduce over the low log2(NS) lane bits.
template<int NS>
__device__ __forceinline__ float allreduce_seg(float v) {
    if constexpr (NS > 1)
        v += __int_as_float(__builtin_amdgcn_update_dpp(
                0, __float_as_int(v), 0xB1, 0xF, 0xF, true));   // quad_perm xor 1
    if constexpr (NS > 2)
        v += __int_as_float(__builtin_amdgcn_update_dpp(
                0, __float_as_int(v), 0x4E, 0xF, 0xF, true));   // quad_perm xor 2
    if constexpr (NS > 4)
        v += __int_as_float(__builtin_amdgcn_ds_swizzle(
                __float_as_int(v), 0x101F));                    // xor 4
    return v;
}

// Conflict-free LDS layout: float4 #k4 of segment seg at float offset
// (k4*NS+seg)*4. perm_idx: logical element j -> stored float offset.
template<int NS, int KSEG>
__device__ __forceinline__ int perm_idx(int j) {
    return (((j % KSEG) >> 2) * NS + (j / KSEG)) * 4 + (j & 3);
}

// ---------------- Layer 1: full-width scan (all 512 threads) ----------------
// NS=4, U=128: thread (u=tid>>2, seg=tid&3) owns 4 gate cols {u,128+u,256+u,384+u}.
// Writes h1 sequence to seq[t] in perm<4,32> layout (layer-2's read geometry).
__device__ void run_l1(const float* __restrict__ Wk, const float* __restrict__ Wr,
                       const float* __restrict__ bias, const float* __restrict__ xg,
                       float* __restrict__ seq, float* __restrict__ xh,
                       float* __restrict__ xring, int tid)
{
    constexpr int U = 128, COLS = 512, NPI = 8, NPH = 16, NP = NPI + NPH;
    const int seg = tid & 3;
    const int u   = tid >> 2;

    f32x2 w[4][NP];
#pragma unroll
    for (int q = 0; q < NPI; ++q) {
        const int k0 = seg * 16 + 2 * q;
#pragma unroll
        for (int g = 0; g < 4; ++g)
            w[g][q] = f32x2{Wk[(size_t)k0 * COLS + g * U + u],
                            Wk[(size_t)(k0 + 1) * COLS + g * U + u]};
    }
#pragma unroll
    for (int q = 0; q < NPH; ++q) {
        const int k0 = seg * 32 + 2 * q;
#pragma unroll
        for (int g = 0; g < 4; ++g)
            w[g][NPI + q] = f32x2{Wr[(size_t)k0 * COLS + g * U + u],
                                  Wr[(size_t)(k0 + 1) * COLS + g * U + u]};
    }
    float bz[4];
#pragma unroll
    for (int g = 0; g < 4; ++g) bz[g] = bias[g * U + u];
#pragma unroll
    for (int g = 0; g < 4; ++g)
#pragma unroll
        for (int q = 0; q < NP; ++q)
            asm volatile("" : "+v"(w[g][q]));

    float cst = 0.0f;

    for (int t = 0; t < TSTEPS; ++t) {
        const float* __restrict__ xr = xh + (t & 1) * 128;
        float* __restrict__ xw       = xh + ((t + 1) & 1) * 128;

        float xstage = 0.0f;
        if (tid < 64 && (t + 1) < TSTEPS) xstage = xg[(t + 1) * 64 + tid];

        f32x2 ac0 = {0.f,0.f}, ac1 = {0.f,0.f}, ac2 = {0.f,0.f}, ac3 = {0.f,0.f};

        // input part: x[t] from xring (perm<4,16>)
        {
            const float4* in4 = reinterpret_cast<const float4*>(xring + (t & 1) * 64) + seg;
#pragma unroll
            for (int k = 0; k < 4; ++k) {
                const float4 v = in4[k * 4];
                const f32x2 lo = {v.x, v.y}, hi = {v.z, v.w};
                pkfma(ac0, w[0][2*k],   lo); pkfma(ac0, w[0][2*k+1], hi);
                pkfma(ac1, w[1][2*k],   lo); pkfma(ac1, w[1][2*k+1], hi);
                pkfma(ac2, w[2][2*k],   lo); pkfma(ac2, w[2][2*k+1], hi);
                pkfma(ac3, w[3][2*k],   lo); pkfma(ac3, w[3][2*k+1], hi);
            }
        }
        // recurrent part: h1[t-1] from xh (perm<4,32>)
        {
            const float4* h4 = reinterpret_cast<const float4*>(xr) + seg;
#pragma unroll
            for (int k = 0; k < 8; ++k) {
                const float4 v = h4[k * 4];
                const f32x2 lo = {v.x, v.y}, hi = {v.z, v.w};
                const int pb = NPI + 2 * k;
                pkfma(ac0, w[0][pb], lo); pkfma(ac0, w[0][pb+1], hi);
                pkfma(ac1, w[1][pb], lo); pkfma(ac1, w[1][pb+1], hi);
                pkfma(ac2, w[2][pb], lo); pkfma(ac2, w[2][pb+1], hi);
                pkfma(ac3, w[3][pb], lo); pkfma(ac3, w[3][pb+1], hi);
            }
        }
        float a0 = allreduce_seg<4>(ac0[0] + ac0[1]) + bz[0];
        float a1 = allreduce_seg<4>(ac1[0] + ac1[1]) + bz[1];
        float a2 = allreduce_seg<4>(ac2[0] + ac2[1]) + bz[2];
        float a3 = allreduce_seg<4>(ac3[0] + ac3[1]) + bz[3];

        const float gi = sigmoidf_(a0);
        const float gf = sigmoidf_(a1);
        const float gg = fmaxf(a2, 0.0f);
        const float go = sigmoidf_(a3);
        cst = fmaf(gf, cst, gi * gg);
        const float h = go * fmaxf(cst, 0.0f);

        if (seg == 0) {
            const int pj = perm_idx<4, 32>(u);
            xw[pj] = h;
            seq[t * 128 + pj] = h;
        }
        if (tid < 64 && (t + 1) < TSTEPS)
            xring[((t + 1) & 1) * 64 + perm_idx<4, 16>(tid)] = xstage;
        __syncthreads();
    }
}

// ---------------- Fused L2 loop (threads 0..255): 290 intervals ----------------
// L2[t=i]: reads seq[i] (perm<4,32>) + xh2[(i-1)&1]; writes xh2[i&1].
__device__ void fused_l2(const float* __restrict__ Wk, const float* __restrict__ Wr,
                         const float* __restrict__ bias,
                         const float* __restrict__ seq, float* __restrict__ xh2,
                         int lt)
{
    constexpr int U = 64, COLS = 256, NPI = 16, NPH = 8, NP = NPI + NPH;
    const int seg = lt & 3;
    const int u   = lt >> 2;

    f32x2 w[4][NP];
#pragma unroll
    for (int q = 0; q < NPI; ++q) {
        const int k0 = seg * 32 + 2 * q;
#pragma unroll
        for (int g = 0; g < 4; ++g)
            w[g][q] = f32x2{Wk[(size_t)k0 * COLS + g * U + u],
                            Wk[(size_t)(k0 + 1) * COLS + g * U + u]};
    }
#pragma unroll
    for (int q = 0; q < NPH; ++q) {
        const int k0 = seg * 16 + 2 * q;
#pragma unroll
        for (int g = 0; g < 4; ++g)
            w[g][NPI + q] = f32x2{Wr[(size_t)k0 * COLS + g * U + u],
                                  Wr[(size_t)(k0 + 1) * COLS + g * U + u]};
    }
    float bz[4];
#pragma unroll
    for (int g = 0; g < 4; ++g) bz[g] = bias[g * U + u];
#pragma unroll
    for (int g = 0; g < 4; ++g)
#pragma unroll
        for (int q = 0; q < NP; ++q)
            asm volatile("" : "+v"(w[g][q]));

    float cst = 0.0f;

    for (int i = 0; i < TSTEPS + 2; ++i) {
        if (i < TSTEPS) {
            f32x2 ac0 = {0.f,0.f}, ac1 = {0.f,0.f}, ac2 = {0.f,0.f}, ac3 = {0.f,0.f};
            {
                const float4* in4 = reinterpret_cast<const float4*>(seq + i * 128) + seg;
#pragma unroll
                for (int k = 0; k < 8; ++k) {
                    const float4 v = in4[k * 4];
                    const f32x2 lo = {v.x, v.y}, hi = {v.z, v.w};
                    pkfma(ac0, w[0][2*k],   lo); pkfma(ac0, w[0][2*k+1], hi);
                    pkfma(ac1, w[1][2*k],   lo); pkfma(ac1, w[1][2*k+1], hi);
                    pkfma(ac2, w[2][2*k],   lo); pkfma(ac2, w[2][2*k+1], hi);
                    pkfma(ac3, w[3][2*k],   lo); pkfma(ac3, w[3][2*k+1], hi);
                }
            }
            {
                const float4* h4 = reinterpret_cast<const float4*>(xh2 + ((i + 1) & 1) * 64) + seg;
#pragma unroll
                for (int k = 0; k < 4; ++k) {
                    const float4 v = h4[k * 4];
                    const f32x2 lo = {v.x, v.y}, hi = {v.z, v.w};
                    const int pb = NPI + 2 * k;
                    pkfma(ac0, w[0][pb], lo); pkfma(ac0, w[0][pb+1], hi);
                    pkfma(ac1, w[1][pb], lo); pkfma(ac1, w[1][pb+1], hi);
                    pkfma(ac2, w[2][pb], lo); pkfma(ac2, w[2][pb+1], hi);
                    pkfma(ac3, w[3][pb], lo); pkfma(ac3, w[3][pb+1], hi);
                }
            }
            float a0 = allreduce_seg<4>(ac0[0] + ac0[1]) + bz[0];
            float a1 = allreduce_seg<4>(ac1[0] + ac1[1]) + bz[1];
            float a2 = allreduce_seg<4>(ac2[0] + ac2[1]) + bz[2];
            float a3 = allreduce_seg<4>(ac3[0] + ac3[1]) + bz[3];

            const float gi = sigmoidf_(a0);
            const float gf = sigmoidf_(a1);
            const float gg = fmaxf(a2, 0.0f);
            const float go = sigmoidf_(a3);
            cst = fmaf(gf, cst, gi * gg);
            const float h = go * fmaxf(cst, 0.0f);

            if (seg == 0) xh2[(i & 1) * 64 + perm_idx<4, 16>(u)] = h;
        }
        __syncthreads();
    }
}

// ------------- Fused L3+L4 loop (threads 256..511): 290 intervals -------------
// L3[t=i-1]: reads xh2[(i-1)&1] + xh3 rec slot (i&1); writes xh3[(i-1)&1].
// L4[t=i-2]: reads xh3[(i-2)&1] (= i&1) + xh4 rec slot ((i-1)&1); writes xh4[i&1].
__device__ void fused_l34(const float* __restrict__ W3k, const float* __restrict__ W3r,
                          const float* __restrict__ b3,
                          const float* __restrict__ W4k, const float* __restrict__ W4r,
                          const float* __restrict__ b4,
                          const float* __restrict__ xh2, float* __restrict__ xh3,
                          float* __restrict__ xh4, int lt)
{
    // L3: NS=4, U=64. L4: NS=8, U=32.
    const int seg3 = lt & 3,  u3 = lt >> 2;
    const int seg4 = lt & 7,  u4 = lt >> 3;

    f32x2 w3[4][16];
#pragma unroll
    for (int q = 0; q < 8; ++q) {                       // input pairs
        const int k0 = seg3 * 16 + 2 * q;
#pragma unroll
        for (int g = 0; g < 4; ++g)
            w3[g][q] = f32x2{W3k[(size_t)k0 * 256 + g * 64 + u3],
                             W3k[(size_t)(k0 + 1) * 256 + g * 64 + u3]};
    }
#pragma unroll
    for (int q = 0; q < 8; ++q) {                       // recurrent pairs
        const int k0 = seg3 * 16 + 2 * q;
#pragma unroll
        for (int g = 0; g < 4; ++g)
            w3[g][8 + q] = f32x2{W3r[(size_t)k0 * 256 + g * 64 + u3],
                                 W3r[(size_t)(k0 + 1) * 256 + g * 64 + u3]};
    }
    f32x2 w4[4][6];
#pragma unroll
    for (int q = 0; q < 4; ++q) {                       // input pairs
        const int k0 = seg4 * 8 + 2 * q;
#pragma unroll
        for (int g = 0; g < 4; ++g)
            w4[g][q] = f32x2{W4k[(size_t)k0 * 128 + g * 32 + u4],
                             W4k[(size_t)(k0 + 1) * 128 + g * 32 + u4]};
    }
#pragma unroll
    for (int q = 0; q < 2; ++q) {                       // recurrent pairs
        const int k0 = seg4 * 4 + 2 * q;
#pragma unroll
        for (int g = 0; g < 4; ++g)
            w4[g][4 + q] = f32x2{W4r[(size_t)k0 * 128 + g * 32 + u4],
                                 W4r[(size_t)(k0 + 1) * 128 + g * 32 + u4]};
    }
    float bz3[4], bz4[4];
#pragma unroll
    for (int g = 0; g < 4; ++g) { bz3[g] = b3[g * 64 + u3]; bz4[g] = b4[g * 32 + u4]; }
#pragma unroll
    for (int g = 0; g < 4; ++g) {
#pragma unroll
        for (int q = 0; q < 16; ++q) asm volatile("" : "+v"(w3[g][q]));
#pragma unroll
        for (int q = 0; q < 6;  ++q) asm volatile("" : "+v"(w4[g][q]));
    }

    float c3 = 0.0f, c4 = 0.0f;

    for (int i = 0; i < TSTEPS + 2; ++i) {
        // ---------------- L3 step t = i-1 ----------------
        if (i >= 1 && i <= TSTEPS) {
            f32x2 ac0 = {0.f,0.f}, ac1 = {0.f,0.f}, ac2 = {0.f,0.f}, ac3 = {0.f,0.f};
            {
                const float4* in4 = reinterpret_cast<const float4*>(xh2 + ((i - 1) & 1) * 64) + seg3;
#pragma unroll
                for (int k = 0; k < 4; ++k) {
                    const float4 v = in4[k * 4];
                    const f32x2 lo = {v.x, v.y}, hi = {v.z, v.w};
                    pkfma(ac0, w3[0][2*k],   lo); pkfma(ac0, w3[0][2*k+1], hi);
                    pkfma(ac1, w3[1][2*k],   lo); pkfma(ac1, w3[1][2*k+1], hi);
                    pkfma(ac2, w3[2][2*k],   lo); pkfma(ac2, w3[2][2*k+1], hi);
                    pkfma(ac3, w3[3][2*k],   lo); pkfma(ac3, w3[3][2*k+1], hi);
                }
            }
            {
                const float4* h4 = reinterpret_cast<const float4*>(xh3 + (i & 1) * 64) + seg3;
#pragma unroll
                for (int k = 0; k < 4; ++k) {
                    const float4 v = h4[k * 4];
                    const f32x2 lo = {v.x, v.y}, hi = {v.z, v.w};
                    const int pb = 8 + 2 * k;
                    pkfma(ac0, w3[0][pb], lo); pkfma(ac0, w3[0][pb+1], hi);
                    pkfma(ac1, w3[1][pb], lo); pkfma(ac1, w3[1][pb+1], hi);
                    pkfma(ac2, w3[2][pb], lo); pkfma(ac2, w3[2][pb+1], hi);
                    pkfma(ac3, w3[3][pb], lo); pkfma(ac3, w3[3][pb+1], hi);
                }
            }
            float a0 = allreduce_seg<4>(ac0[0] + ac0[1]) + bz3[0];
            float a1 = allreduce_seg<4>(ac1[0] + ac1[1]) + bz3[1];
            float a2 = allreduce_seg<4>(ac2[0] + ac2[1]) + bz3[2];
            float a3 = allreduce_seg<4>(ac3[0] + ac3[1]) + bz3[3];
            const float gi = sigmoidf_(a0);
            const float gf = sigmoidf_(a1);
            const float gg = fmaxf(a2, 0.0f);
            const float go = sigmoidf_(a3);
            c3 = fmaf(gf, c3, gi * gg);
            const float h = go * fmaxf(c3, 0.0f);
            if (seg3 == 0) xh3[((i - 1) & 1) * 64 + perm_idx<4, 16>(u3)] = h;
        }
        // ---------------- L4 step t = i-2 ----------------
        if (i >= 2) {
            f32x2 ac0 = {0.f,0.f}, ac1 = {0.f,0.f}, ac2 = {0.f,0.f}, ac3 = {0.f,0.f};
            {
                const float4* in4 = reinterpret_cast<const float4*>(xh3 + (i & 1) * 64);
#pragma unroll
                for (int k = 0; k < 2; ++k) {
                    const float4 v = in4[((seg4 & 1) * 2 + k) * 4 + (seg4 >> 1)];
                    const f32x2 lo = {v.x, v.y}, hi = {v.z, v.w};
                    pkfma(ac0, w4[0][2*k],   lo); pkfma(ac0, w4[0][2*k+1], hi);
                    pkfma(ac1, w4[1][2*k],   lo); pkfma(ac1, w4[1][2*k+1], hi);
                    pkfma(ac2, w4[2][2*k],   lo); pkfma(ac2, w4[2][2*k+1], hi);
                    pkfma(ac3, w4[3][2*k],   lo); pkfma(ac3, w4[3][2*k+1], hi);
                }
            }
            {
                const float4 v = reinterpret_cast<const float4*>(xh4 + ((i - 1) & 1) * 32)[seg4];
                const f32x2 lo = {v.x, v.y}, hi = {v.z, v.w};
                pkfma(ac0, w4[0][4], lo); pkfma(ac0, w4[0][5], hi);
                pkfma(ac1, w4[1][4], lo); pkfma(ac1, w4[1][5], hi);
                pkfma(ac2, w4[2][4], lo); pkfma(ac2, w4[2][5], hi);
                pkfma(ac3, w4[3][4], lo); pkfma(ac3, w4[3][5], hi);
            }
            float a0 = allreduce_seg<8>(ac0[0] + ac0[1]) + bz4[0];
            float a1 = allreduce_seg<8>(ac1[0] + ac1[1]) + bz4[1];
            float a2 = allreduce_seg<8>(ac2[0] + ac2[1]) + bz4[2];
            float a3 = allreduce_seg<8>(ac3[0] + ac3[1]) + bz4[3];
            const float gi = sigmoidf_(a0);
            const float gf = sigmoidf_(a1);
            const float gg = fmaxf(a2, 0.0f);
            const float go = sigmoidf_(a3);
            c4 = fmaf(gf, c4, gi * gg);
            const float h = go * fmaxf(c4, 0.0f);
            if (seg4 == 0) xh4[(i & 1) * 32 + u4] = h;   // perm<8,4> = identity
        }
        __syncthreads();
    }
}

extern "C" __global__ void __launch_bounds__(NTHREADS, 2)
lstm_stack_kernel(const float* __restrict__ x,
                  const float* __restrict__ W1, const float* __restrict__ U1, const float* __restrict__ b1,
                  const float* __restrict__ W2, const float* __restrict__ U2, const float* __restrict__ b2,
                  const float* __restrict__ W3, const float* __restrict__ U3, const float* __restrict__ b3,
                  const float* __restrict__ W4, const float* __restrict__ U4, const float* __restrict__ b4,
                  const float* __restrict__ Wf, const float* __restrict__ bf,
                  const float* __restrict__ Wo, const float* __restrict__ bo,
                  float* __restrict__ out)
{
    __shared__ __align__(16) float seq[TSTEPS * 128];   // 147456 B (h1 sequence)
    __shared__ __align__(16) float xh1[2 * 128];
    __shared__ __align__(16) float xring[2 * 64];
    __shared__ __align__(16) float xh2[2 * 64];
    __shared__ __align__(16) float xh3[2 * 64];
    __shared__ __align__(16) float xh4[2 * 32];
    __shared__ __align__(16) float hbuf[16];

    const int tid = threadIdx.x;
    const float* xg = x + (size_t)blockIdx.x * TSTEPS * 64;

    // prologue: zero state buffers, stage x row 0
    if (tid < 128) xh1[tid] = 0.0f;
    if (tid < 64) {
        xring[perm_idx<4, 16>(tid)] = xg[tid];
        xh2[64 + tid] = 0.0f;
        xh3[64 + tid] = 0.0f;
    }
    if (tid < 32) xh4[32 + tid] = 0.0f;
    __syncthreads();

    // phase A: layer 1 full scan (288 intervals)
    run_l1(W1, U1, b1, xg, seq, xh1, xring, tid);

    // phase B: fused L2 || L3 || L4 skewed pipeline (290 intervals)
    if (tid < 256) fused_l2(W2, U2, b2, seq, xh2, tid);
    else           fused_l34(W3, U3, b3, W4, U4, b4, xh2, xh3, xh4, tid - 256);
    __syncthreads();

    // FC head: final h4 is xh4 slot 1 (last write at i=289, 289&1==1)
    if (tid < 16) {
        float acc = bf[tid];
#pragma unroll
        for (int k = 0; k < 32; ++k) acc = fmaf(xh4[32 + k], Wf[k * 16 + tid], acc);
        hbuf[tid] = fmaxf(acc, 0.0f);
    }
    __syncthreads();
    if (tid == 0) {
        float acc = bo[0];
#pragma unroll
        for (int k = 0; k < 16; ++k) acc = fmaf(hbuf[k], Wo[k], acc);
        out[blockIdx.x] = acc;
    }
}

extern "C" void kernel_launch(void* const* d_in, const int* in_sizes, int n_in,
                              void* d_out, int out_size, void* d_ws, size_t ws_size,
                              hipStream_t stream) {
    const float* x  = (const float*)d_in[0];
    const float* W1 = (const float*)d_in[1];
    const float* U1 = (const float*)d_in[2];
    const float* b1 = (const float*)d_in[3];
    const float* W2 = (const float*)d_in[4];
    const float* U2 = (const float*)d_in[5];
    const float* b2 = (const float*)d_in[6];
    const float* W3 = (const float*)d_in[7];
    const float* U3 = (const float*)d_in[8];
    const float* b3 = (const float*)d_in[9];
    const float* W4 = (const float*)d_in[10];
    const float* U4 = (const float*)d_in[11];
    const float* b4 = (const float*)d_in[12];
    const float* Wf = (const float*)d_in[13];
    const float* bf = (const float*)d_in[14];
    const float* Wo = (const float*)d_in[15];
    const float* bo = (const float*)d_in[16];
    float* out = (float*)d_out;

    lstm_stack_kernel<<<dim3(256), dim3(NTHREADS), 0, stream>>>(
        x, W1, U1, b1, W2, U2, b2, W3, U3, b3, W4, U4, b4, Wf, bf, Wo, bo, out);
}